// Round 11
// baseline (528.522 us; speedup 1.0000x reference)
//
#include <hip/hip_runtime.h>
#include <hip/hip_bf16.h>
#include <cstddef>
#include <cstdint>

// Problem constants
static constexpr int NB  = 4;       // batch
static constexpr int CH  = 512;     // planes
static constexpr int HH  = 128;
static constexpr int WWi = 128;
static constexpr int HW  = HH * WWi;   // 16384
static constexpr int Qd  = 128;     // q
static constexpr int Q2d = 256;     // 2q

typedef __attribute__((ext_vector_type(8))) short bf8;   // 8 bf16 (4 VGPRs)
typedef __attribute__((ext_vector_type(4))) float f4;    // MFMA accumulator

__device__ __forceinline__ short f2bf(float x) {
  __hip_bfloat16 h = __float2bfloat16(x);
  short s; __builtin_memcpy(&s, &h, 2); return s;
}
__device__ __forceinline__ float bfs2f(short u) {
  union { unsigned int i; float f; } x;
  x.i = ((unsigned int)(unsigned short)u) << 16; return x.f;
}

// ---------------- depthwise 3x3 stride-2 conv + BN, 4 outputs/thread (validated R5) ----------------
__launch_bounds__(256)
__global__ void dw_conv_bn4(const float* __restrict__ in, float* __restrict__ out,
                            const float* __restrict__ wgt, const float* __restrict__ s,
                            const float* __restrict__ b, int Hi, int Wi, int Ho, int Wo4) {
  int idx = blockIdx.x * 256 + threadIdx.x;   // NB*CH*Ho*Wo4
  int q = idx % Wo4; int t = idx / Wo4;
  int ho = t % Ho; t /= Ho;
  int c = t % CH;
  const float* ip = in + (size_t)t * Hi * Wi;
  const float* wp = wgt + c * 9;
  float w[9];
#pragma unroll
  for (int k = 0; k < 9; k++) w[k] = wp[k];
  const int x0 = q * 8;
  float acc0 = 0.f, acc1 = 0.f, acc2 = 0.f, acc3 = 0.f;
#pragma unroll
  for (int kh = 0; kh < 3; kh++) {
    int y = ho * 2 - 1 + kh;
    if ((unsigned)y < (unsigned)Hi) {
      const float* row = ip + (size_t)y * Wi + x0;
      float4 v0 = *(const float4*)row;
      float4 v1 = *(const float4*)(row + 4);
      float left = (x0 > 0) ? row[-1] : 0.f;
      float xs[9] = {left, v0.x, v0.y, v0.z, v0.w, v1.x, v1.y, v1.z, v1.w};
      const float w0 = w[kh * 3 + 0], w1 = w[kh * 3 + 1], w2 = w[kh * 3 + 2];
      acc0 += w0 * xs[0] + w1 * xs[1] + w2 * xs[2];
      acc1 += w0 * xs[2] + w1 * xs[3] + w2 * xs[4];
      acc2 += w0 * xs[4] + w1 * xs[5] + w2 * xs[6];
      acc3 += w0 * xs[6] + w1 * xs[7] + w2 * xs[8];
    }
  }
  const float sc = s[c], bb = b[c];
  float4 o;
  o.x = acc0 * sc + bb; o.y = acc1 * sc + bb;
  o.z = acc2 * sc + bb; o.w = acc3 * sc + bb;
  *(float4*)(out + (size_t)idx * 4) = o;
}

// ---------------- horizontal bilinear expand (validated) ----------------
__launch_bounds__(256)
__global__ void lrow_kernel(const float* __restrict__ lcam, float* __restrict__ lrow) {
  int idx = blockIdx.x * 256 + threadIdx.x;  // 4*512*16*128
  int wcol = idx & 127; int t = idx >> 7;
  int hy = t & 15; t >>= 4;
  float pos = wcol * (15.f / 127.f);
  int x0 = (int)pos; if (x0 > 15) x0 = 15;
  float tx = pos - x0;
  int x1 = x0 + 1; if (x1 > 15) x1 = 15;
  const float* lc = lcam + ((size_t)t * 16 + hy) * 16;
  lrow[idx] = lc[x0] * (1.f - tx) + lc[x1] * tx;
}

// ---------------- f32 -> bf16 convert (validated) ----------------
__launch_bounds__(256)
__global__ void cvt_f32_bf16(const float* __restrict__ in, short* __restrict__ out, int n4) {
  int i = blockIdx.x * 256 + threadIdx.x;
  if (i >= n4) return;
  float4 v = ((const float4*)in)[i];
  short tmp[4] = {f2bf(v.x), f2bf(v.y), f2bf(v.z), f2bf(v.w)};
  short4 o; __builtin_memcpy(&o, tmp, 8);
  ((short4*)out)[i] = o;
}

// ---------------- MFMA staging helpers, K_STEP = 64 (round-0, conflict-free) ----------------
// LDS tile [128 rows][64 k] bf16 (16KB); 8 16B-slots/row.
// Round-9 swizzle: perm = slot ^ (((row>>1) ^ (row>>3)) & 7).
// Reads stay 2-way (free). DO NOT pack transpose writes wider (R1 regression).
// DO NOT force occupancy via launch_bounds min-waves (R3 regression: scratch spills).
// DO NOT add secondary transposed outputs to MFMA epilogues (R8 regression).
// R10: counted-vmcnt pipelining = neutral (latency already hidden by 3 blocks/CU).
// R11: LDS-pipe is the bound (24 LDS ops vs 32 MFMA per thread/K-step) -> small
// L2/L3-resident linear operands are loaded DIRECTLY into fragments, not via LDS.
__device__ __forceinline__ int sls(int row, int slot) {
  return row * 64 + ((slot ^ (((row >> 1) ^ (row >> 3)) & 7)) << 3);
}

// DMA stage via global_load_lds (16B): linear LDS dest + INVERSE-swizzled
// per-lane global source (T21: both-sides-or-neither; XOR is an involution).
// LDS byte image == sls layout, so the fragld64 read path is unchanged.
__device__ __forceinline__ void stg64_dma(const short* __restrict__ src, size_t stride,
                                          int kb, short* lds, int t) {
  const int lane = t & 63, w = t >> 6;
#pragma unroll
  for (int i2 = 0; i2 < 4; i2++) {
    int r0 = w * 32 + i2 * 8;                 // wave-uniform base row
    int row = r0 + (lane >> 3);
    int sl = (lane & 7) ^ (((row >> 1) ^ (row >> 3)) & 7);
    const short* g = src + (size_t)row * stride + kb + sl * 8;
    short* l = lds + r0 * 64;                 // wave-uniform; HW adds lane*16B
    __builtin_amdgcn_global_load_lds(
        (const __attribute__((address_space(1))) unsigned int*)g,
        (__attribute__((address_space(3))) unsigned int*)l, 16, 0, 0);
  }
}

// contiguous bf16 source rows (VGPR path; kept for non-DMA users)
__device__ __forceinline__ void stg64_b16(const short* __restrict__ src, size_t stride,
                                          int kb, short* lds, int t) {
#pragma unroll
  for (int i = 0; i < 4; i++) {
    int chunk = t + i * 256;            // 1024 chunks = 128 rows x 8 slots
    int row = chunk >> 3, slot = chunk & 7;
    bf8 v = *(const bf8*)(src + (size_t)row * stride + kb + slot * 8);
    *(bf8*)(lds + sls(row, slot)) = v;
  }
}
// contiguous f32 source rows + cvt
__device__ __forceinline__ void stg64_f32(const float* __restrict__ src, size_t stride,
                                          int kb, short* lds, int t) {
#pragma unroll
  for (int i = 0; i < 4; i++) {
    int chunk = t + i * 256;
    int row = chunk >> 3, slot = chunk & 7;
    const float* sp = src + (size_t)row * stride + kb + slot * 8;
    float4 v0 = *(const float4*)sp, v1 = *(const float4*)(sp + 4);
    union { short s[8]; bf8 v; } u;
    u.s[0] = f2bf(v0.x); u.s[1] = f2bf(v0.y); u.s[2] = f2bf(v0.z); u.s[3] = f2bf(v0.w);
    u.s[4] = f2bf(v1.x); u.s[5] = f2bf(v1.y); u.s[6] = f2bf(v1.z); u.s[7] = f2bf(v1.w);
    *(bf8*)(lds + sls(row, slot)) = u.v;
  }
}
// f32 TRANSPOSE stage (coalesced): lds[p][c] <- src[c][pb+p]
__device__ __forceinline__ void stg64_t32(const float* __restrict__ src, size_t sstride,
                                          int pb, short* lds, int t) {
#pragma unroll
  for (int i2 = 0; i2 < 4; i2++) {
    int chunk = t + i2 * 256;           // 1024 chunks = 64 c x 16 p-groups
    int c = (chunk >> 3) & 63;
    int p8 = ((chunk & 7) | ((chunk >> 6) & 8)) * 8;
    const float* fr = src + (size_t)c * sstride + pb + p8;
    float4 f0 = *(const float4*)fr, f1 = *(const float4*)(fr + 4);
    float fv[8];
    __builtin_memcpy(&fv[0], &f0, 16); __builtin_memcpy(&fv[4], &f1, 16);
    int slot = c >> 3, eidx = c & 7;
#pragma unroll
    for (int e = 0; e < 8; e++) {
      lds[sls(p8 + e, slot) + eidx] = f2bf(fv[e]);
    }
  }
}
// bf16 TRANSPOSE stage (coalesced): lds[p][c] <- src[c][pb+p]
__device__ __forceinline__ void stg64_t16(const short* __restrict__ src, size_t sstride,
                                          int pb, short* lds, int t) {
#pragma unroll
  for (int i2 = 0; i2 < 4; i2++) {
    int chunk = t + i2 * 256;
    int c = (chunk >> 3) & 63;
    int p8 = ((chunk & 7) | ((chunk >> 6) & 8)) * 8;
    bf8 v = *(const bf8*)(src + (size_t)c * sstride + pb + p8);
    int slot = c >> 3, eidx = c & 7;
#pragma unroll
    for (int e = 0; e < 8; e++) {
      lds[sls(p8 + e, slot) + eidx] = v[e];
    }
  }
}
__device__ __forceinline__ bf8 fragld64(const short* lds, int row, int kk, int lg) {
  return *(const bf8*)(lds + sls(row, kk * 4 + lg));
}
// Direct global fragment load (linear [row][stride] bf16 source).
// Identical bytes to stg64_dma/stg64_b16 + fragld64: src[row*stride + kb + kk*32 + lg*8].
__device__ __forceinline__ bf8 fragld_g(const short* __restrict__ src, size_t stride,
                                        int kb, int row, int kk, int lg) {
  return *(const bf8*)(src + (size_t)row * stride + kb + kk * 32 + lg * 8);
}

// ---------------- slf precompute (TRANSPOSED): slfb_T[n][h'][w][c] (validated R6) ----------------
__launch_bounds__(256)
__global__ void slf_build_T(const float* __restrict__ feat, const float* __restrict__ lrw,
                            short* __restrict__ slfbT, int h0) {
  const int cb = blockIdx.x * 64;     // c block (8 of 512)
  const int hh = blockIdx.y;          // h' 0..63
  const int n  = blockIdx.z;
  const int h  = hh + h0;
  const int t  = threadIdx.x;
  __shared__ __align__(16) short lT[8192];   // [w=128][c=64] swizzled
  const float posy = h * (15.f / 127.f);
  int hy0 = (int)posy; if (hy0 > 15) hy0 = 15;
  int hy1 = hy0 + 1; if (hy1 > 15) hy1 = 15;
  const float tyv = posy - hy0;
#pragma unroll
  for (int i2 = 0; i2 < 4; i2++) {
    int chunk = t + i2 * 256;           // 64 c x 16 w-groups
    int c = (chunk >> 3) & 63;
    int w8 = ((chunk & 7) | ((chunk >> 6) & 8)) * 8;
    size_t cidx = (size_t)(n * CH) + cb + c;
    const float* fr = feat + cidx * HW + h * WWi + w8;
    const float* l0r = lrw + (cidx * 16 + hy0) * WWi + w8;
    const float* l1r = lrw + (cidx * 16 + hy1) * WWi + w8;
    float4 f0 = *(const float4*)fr, f1 = *(const float4*)(fr + 4);
    float4 a0 = *(const float4*)l0r, a1 = *(const float4*)(l0r + 4);
    float4 b0 = *(const float4*)l1r, b1 = *(const float4*)(l1r + 4);
    float fv[8], av[8], bv[8];
    __builtin_memcpy(&fv[0], &f0, 16); __builtin_memcpy(&fv[4], &f1, 16);
    __builtin_memcpy(&av[0], &a0, 16); __builtin_memcpy(&av[4], &a1, 16);
    __builtin_memcpy(&bv[0], &b0, 16); __builtin_memcpy(&bv[4], &b1, 16);
    int slot = c >> 3, eidx = c & 7;
#pragma unroll
    for (int e = 0; e < 8; e++) {
      float v = fv[e] * (1.f + av[e] + (bv[e] - av[e]) * tyv);
      lT[sls(w8 + e, slot) + eidx] = f2bf(v);
    }
  }
  __syncthreads();
#pragma unroll
  for (int i2 = 0; i2 < 4; i2++) {
    int chunk = t + i2 * 256;           // 128 w x 8 slots
    int w = chunk >> 3, slot = chunk & 7;
    bf8 v = *(const bf8*)(lT + sls(w, slot));
    *(bf8*)(slfbT + (((size_t)(n * 64) + hh) * WWi + w) * CH + cb + slot * 8) = v;
  }
}

// ---------------- CAM via MFMA (validated r8) ----------------
__launch_bounds__(256)
__global__ void energy_mfma(const float* __restrict__ l3, float* __restrict__ energy) {
  const int c0 = blockIdx.x * 128;
  const int d0 = blockIdx.y * 128;
  const int n = blockIdx.z;
  const int t = threadIdx.x;
  const int lane16 = t & 15, lg = (t >> 4) & 3, wave = t >> 6;
  const int wm = (wave >> 1) * 64, wn = (wave & 1) * 64;
  __shared__ __align__(16) short lA[8192], lB[8192];
  const float* srcA = l3 + ((size_t)n * CH + c0) * 256;
  const float* srcB = l3 + ((size_t)n * CH + d0) * 256;
  f4 acc[4][4];
#pragma unroll
  for (int i = 0; i < 4; i++)
#pragma unroll
    for (int j = 0; j < 4; j++) acc[i][j] = (f4)0.f;
  for (int kb = 0; kb < 256; kb += 64) {
    stg64_f32(srcA, 256, kb, lA, t);
    stg64_f32(srcB, 256, kb, lB, t);
    __syncthreads();
#pragma unroll
    for (int kk = 0; kk < 2; kk++) {
      bf8 av[4], bv[4];
#pragma unroll
      for (int i = 0; i < 4; i++) av[i] = fragld64(lA, wm + i * 16 + lane16, kk, lg);
#pragma unroll
      for (int j = 0; j < 4; j++) bv[j] = fragld64(lB, wn + j * 16 + lane16, kk, lg);
#pragma unroll
      for (int i = 0; i < 4; i++)
#pragma unroll
        for (int j = 0; j < 4; j++)
          acc[i][j] = __builtin_amdgcn_mfma_f32_16x16x32_bf16(av[i], bv[j], acc[i][j], 0, 0, 0);
    }
    __syncthreads();
  }
#pragma unroll
  for (int i = 0; i < 4; i++)
#pragma unroll
    for (int j = 0; j < 4; j++) {
      int d = d0 + wn + j * 16 + lane16;
#pragma unroll
      for (int r = 0; r < 4; r++) {
        int c = c0 + wm + i * 16 + lg * 4 + r;
        energy[((size_t)n * CH + c) * CH + d] = acc[i][j][r];
      }
    }
}

__launch_bounds__(256)
__global__ void softmax_attn(float* __restrict__ energy) {
  float* row = energy + (size_t)blockIdx.x * CH;   // 2048 rows of 512
  int t = threadIdx.x;
  __shared__ float red[256];
  float e0 = row[t], e1 = row[t + 256];
  red[t] = fminf(e0, e1);
  __syncthreads();
  for (int s = 128; s > 0; s >>= 1) {
    if (t < s) red[t] = fminf(red[t], red[t + s]);
    __syncthreads();
  }
  float emin = red[0];
  __syncthreads();
  float w0 = __expf(emin - e0), w1 = __expf(emin - e1);
  red[t] = w0 + w1;
  __syncthreads();
  for (int s = 128; s > 0; s >>= 1) {
    if (t < s) red[t] += red[t + s];
    __syncthreads();
  }
  float inv = 1.f / red[0];
  row[t] = w0 * inv;
  row[t + 256] = w1 * inv;
}

__launch_bounds__(256)
__global__ void cam_mfma(const float* __restrict__ attn, const float* __restrict__ l3,
                         const float* __restrict__ gamma, float* __restrict__ lcam) {
  const int pb = blockIdx.x * 128;
  const int mb = blockIdx.y * 128;
  const int n = blockIdx.z;
  const int t = threadIdx.x;
  const int lane16 = t & 15, lg = (t >> 4) & 3, wave = t >> 6;
  const int wm = (wave >> 1) * 64, wn = (wave & 1) * 64;
  __shared__ __align__(16) short lA[8192], lB[8192];
  const float* srcA = attn + ((size_t)n * CH + mb) * CH;
  const float gm = gamma[0];
  f4 acc[4][4];
#pragma unroll
  for (int i = 0; i < 4; i++)
#pragma unroll
    for (int j = 0; j < 4; j++) acc[i][j] = (f4)0.f;
  for (int kb = 0; kb < 512; kb += 64) {
    stg64_f32(srcA, CH, kb, lA, t);                                     // A: attn[c][d]
    stg64_t32(l3 + ((size_t)n * CH + kb) * 256, 256, pb, lB, t);        // B: l3[d][p] -> [p][d]
    __syncthreads();
#pragma unroll
    for (int kk = 0; kk < 2; kk++) {
      bf8 av[4], bv[4];
#pragma unroll
      for (int i = 0; i < 4; i++) av[i] = fragld64(lA, wm + i * 16 + lane16, kk, lg);
#pragma unroll
      for (int j = 0; j < 4; j++) bv[j] = fragld64(lB, wn + j * 16 + lane16, kk, lg);
#pragma unroll
      for (int i = 0; i < 4; i++)
#pragma unroll
        for (int j = 0; j < 4; j++)
          acc[i][j] = __builtin_amdgcn_mfma_f32_16x16x32_bf16(av[i], bv[j], acc[i][j], 0, 0, 0);
    }
    __syncthreads();
  }
#pragma unroll
  for (int i = 0; i < 4; i++)
#pragma unroll
    for (int j = 0; j < 4; j++) {
      int p = pb + wn + j * 16 + lane16;
#pragma unroll
      for (int r = 0; r < 4; r++) {
        int c = mb + wm + i * 16 + lg * 4 + r;
        size_t idx = ((size_t)n * CH + c) * 256 + p;
        lcam[idx] = gm * acc[i][j][r] + l3[idx];
      }
    }
}

// ---------------- theta MFMA: bmb[n][d][p] bf16 = s*(wth@feat) + b ----------------
// A (wthb, 128KB L2-resident, linear) loaded DIRECTLY into fragments — no LDS.
__launch_bounds__(256)
__global__ void theta_mfma2(const short* __restrict__ wthb, const float* __restrict__ feat,
                            const float* __restrict__ s, const float* __restrict__ b,
                            short* __restrict__ bmb) {
  const int pb = blockIdx.x * 128;
  const int n = blockIdx.y;
  const int t = threadIdx.x;
  const int lane16 = t & 15, lg = (t >> 4) & 3, wave = t >> 6;
  const int wm = (wave >> 1) * 64, wn = (wave & 1) * 64;
  __shared__ __align__(16) short lB[8192];
  f4 acc[4][4];
#pragma unroll
  for (int i = 0; i < 4; i++)
#pragma unroll
    for (int j = 0; j < 4; j++) acc[i][j] = (f4)0.f;
  for (int kb = 0; kb < 512; kb += 64) {
    stg64_t32(feat + ((size_t)(n * CH) + kb) * HW, HW, pb, lB, t);    // B: feat[c][p] -> [p][c]
    __syncthreads();
#pragma unroll
    for (int kk = 0; kk < 2; kk++) {
      bf8 av[4], bv[4];
#pragma unroll
      for (int i = 0; i < 4; i++) av[i] = fragld_g(wthb, 512, kb, wm + i * 16 + lane16, kk, lg);
#pragma unroll
      for (int j = 0; j < 4; j++) bv[j] = fragld64(lB, wn + j * 16 + lane16, kk, lg);
#pragma unroll
      for (int i = 0; i < 4; i++)
#pragma unroll
        for (int j = 0; j < 4; j++)
          acc[i][j] = __builtin_amdgcn_mfma_f32_16x16x32_bf16(av[i], bv[j], acc[i][j], 0, 0, 0);
    }
    __syncthreads();
  }
#pragma unroll
  for (int i = 0; i < 4; i++)
#pragma unroll
    for (int j = 0; j < 4; j++) {
      int p = pb + wn + j * 16 + lane16;
#pragma unroll
      for (int r = 0; r < 4; r++) {
        int d = wm + i * 16 + lg * 4 + r;
        bmb[((size_t)(n * Qd) + d) * HW + p] = f2bf(s[d] * acc[i][j][r] + b[d]);
      }
    }
}

// ---------------- rowsum over bf16 rows ----------------
__launch_bounds__(256)
__global__ void rowsum_bf(const short* __restrict__ bmb, float* __restrict__ rs) {
  int row = blockIdx.x;   // 512 rows (n*Qd + d)
  int t = threadIdx.x;
  const short* r = bmb + (size_t)row * HW;
  float a = 0.f;
  for (int p = t * 8; p < HW; p += 2048) {
    bf8 v = *(const bf8*)(r + p);
#pragma unroll
    for (int e = 0; e < 8; e++) a += bfs2f(v[e]);
  }
  __shared__ float red[256];
  red[t] = a;
  __syncthreads();
  for (int s = 128; s > 0; s >>= 1) {
    if (t < s) red[t] += red[t + s];
    __syncthreads();
  }
  if (t == 0) rs[row] = red[0];
}

// ---------------- M1 MFMA: m1p[kc][n][c][d] = feat @ bmb^T partials (kc=32) ----------------
// B (bmb, bf16 linear rows, L3-resident) loaded DIRECTLY into fragments — no LDS.
// Per-instruction pattern: 16 rows x 64B contiguous — coalesces to 64B segments.
__launch_bounds__(256)
__global__ void m1_mfma2(const float* __restrict__ feat, const short* __restrict__ bmb,
                         float* __restrict__ m1p) {
  const int c0 = blockIdx.x * 128;
  const int kc = blockIdx.y;
  const int n = blockIdx.z;
  const int t = threadIdx.x;
  const int lane16 = t & 15, lg = (t >> 4) & 3, wave = t >> 6;
  const int wm = (wave >> 1) * 64, wn = (wave & 1) * 64;
  __shared__ __align__(16) short lA[8192];
  const float* srcA = feat + ((size_t)(n * CH) + c0) * HW;
  const short* srcB = bmb + (size_t)(n * Qd) * HW;
  f4 acc[4][4];
#pragma unroll
  for (int i = 0; i < 4; i++)
#pragma unroll
    for (int j = 0; j < 4; j++) acc[i][j] = (f4)0.f;
  const int kend = kc * 512 + 512;
  for (int kb = kc * 512; kb < kend; kb += 64) {
    stg64_f32(srcA, HW, kb, lA, t);   // A: feat[c][pos] (f32 cvt, must stage)
    __syncthreads();
#pragma unroll
    for (int kk = 0; kk < 2; kk++) {
      bf8 av[4], bv[4];
#pragma unroll
      for (int i = 0; i < 4; i++) av[i] = fragld64(lA, wm + i * 16 + lane16, kk, lg);
#pragma unroll
      for (int j = 0; j < 4; j++) bv[j] = fragld_g(srcB, HW, kb, wn + j * 16 + lane16, kk, lg);
#pragma unroll
      for (int i = 0; i < 4; i++)
#pragma unroll
        for (int j = 0; j < 4; j++)
          acc[i][j] = __builtin_amdgcn_mfma_f32_16x16x32_bf16(av[i], bv[j], acc[i][j], 0, 0, 0);
    }
    __syncthreads();
  }
#pragma unroll
  for (int i = 0; i < 4; i++)
#pragma unroll
    for (int j = 0; j < 4; j++) {
      int d = wn + j * 16 + lane16;
#pragma unroll
      for (int r = 0; r < 4; r++) {
        int c = c0 + wm + i * 16 + lg * 4 + r;
        m1p[(((size_t)kc * NB + n) * CH + c) * Qd + d] = acc[i][j][r];
      }
    }
}

__launch_bounds__(256)
__global__ void m1_reduce(const float* __restrict__ m1p, float* __restrict__ m1) {
  int idx = blockIdx.x * 256 + threadIdx.x;  // 4*512*128
  float a = 0.f;
#pragma unroll
  for (int kc = 0; kc < 32; kc++) a += m1p[(size_t)kc * (NB * CH * Qd) + idx];
  m1[idx] = a;
}

// ---------------- fused zidt+z3 (validated R8/R9) ----------------
__launch_bounds__(128)
__global__ void z3_fused(const float* __restrict__ m1, const float* __restrict__ wphi,
                         const float* __restrict__ sp, const float* __restrict__ bp,
                         const float* __restrict__ rs, const float* __restrict__ wadj,
                         const float* __restrict__ sa, const float* __restrict__ ba,
                         float* __restrict__ z3) {
  int n = blockIdx.y, c = blockIdx.x, d = threadIdx.x;
  __shared__ float wrow[512];
  __shared__ float zr[128];
  for (int i = d; i < 512; i += 128) wrow[i] = wphi[(size_t)c * 512 + i];
  __syncthreads();
  const float* mb = m1 + (size_t)n * CH * Qd;
  float acc = 0.f;
#pragma unroll 4
  for (int i = 0; i < 512; i++) acc += wrow[i] * mb[i * Qd + d];
  zr[d] = sp[c] * acc + bp[c] * rs[n * Qd + d];
  __syncthreads();
  const float* wr = wadj + (size_t)d * 128;
  float acc2 = 0.f;
#pragma unroll 4
  for (int i = 0; i < 128; i++) acc2 += wr[i] * zr[i];
  z3[((size_t)n * Q2d + c) * Qd + d] = sa[d] * acc2 + ba[d] + zr[d];
}

__launch_bounds__(128)
__global__ void z4_kernel(const float* __restrict__ z3, const float* __restrict__ wwg,
                          const float* __restrict__ sw, const float* __restrict__ bw,
                          float* __restrict__ z4) {
  int n = blockIdx.y, o = blockIdx.x, d = threadIdx.x;
  __shared__ float wrow[256];
  wrow[d] = wwg[(size_t)o * 256 + d];
  wrow[d + 128] = wwg[(size_t)o * 256 + 128 + d];
  __syncthreads();
  const float* zb = z3 + (size_t)n * Q2d * Qd;
  float acc = 0.f;
#pragma unroll 4
  for (int i = 0; i < 256; i++) acc += wrow[i] * zb[i * Qd + d];
  z4[((size_t)n * Q2d + o) * Qd + d] = sw[o] * acc + bw[o];
}

__launch_bounds__(128)
__global__ void wz_kernel(const float* __restrict__ z4, const float* __restrict__ wc3,
                          const float* __restrict__ s3, float* __restrict__ wz) {
  int n = blockIdx.y, o = blockIdx.x, d = threadIdx.x;
  __shared__ float wrow[256];
  wrow[d] = wc3[(size_t)o * 256 + d];
  wrow[d + 128] = wc3[(size_t)o * 256 + 128 + d];
  __syncthreads();
  const float* zb = z4 + (size_t)n * Q2d * Qd;
  float acc = 0.f;
#pragma unroll 4
  for (int i = 0; i < 256; i++) acc += wrow[i] * zb[i * Qd + d];
  wz[((size_t)n * CH + o) * Qd + d] = s3[o] * acc;
}

// ---------------- ygout MFMA: gout_T[n][p][c] bf16 = relu(feat + wz@bmb + b3) ----------------
__launch_bounds__(256)
__global__ void ygout_mfma2(const float* __restrict__ wz, const short* __restrict__ bmb,
                            const float* __restrict__ feat, const float* __restrict__ b3,
                            short* __restrict__ goutT) {
  const int pb = blockIdx.x * 128;
  const int mb = blockIdx.y * 128;
  const int n = blockIdx.z;
  const int t = threadIdx.x;
  const int lane16 = t & 15, lg = (t >> 4) & 3, wave = t >> 6;
  const int wm = (wave >> 1) * 64, wn = (wave & 1) * 64;
  __shared__ __align__(16) short lA[8192], lB[8192];
  const float* srcA = wz + ((size_t)(n * CH) + mb) * Qd;
  f4 acc[4][4];
#pragma unroll
  for (int i = 0; i < 4; i++)
#pragma unroll
    for (int j = 0; j < 4; j++) acc[i][j] = (f4)0.f;
  for (int kb = 0; kb < 128; kb += 64) {
    stg64_f32(srcA, Qd, kb, lA, t);                                   // A: wz[c][d]
    stg64_t16(bmb + ((size_t)(n * Qd) + kb) * HW, HW, pb, lB, t);     // B: bmb[d][p] -> [p][d]
    __syncthreads();
#pragma unroll
    for (int kk = 0; kk < 2; kk++) {
      bf8 av[4], bv[4];
#pragma unroll
      for (int i = 0; i < 4; i++) av[i] = fragld64(lA, wm + i * 16 + lane16, kk, lg);
#pragma unroll
      for (int j = 0; j < 4; j++) bv[j] = fragld64(lB, wn + j * 16 + lane16, kk, lg);
#pragma unroll
      for (int i = 0; i < 4; i++)
#pragma unroll
        for (int j = 0; j < 4; j++)
          acc[i][j] = __builtin_amdgcn_mfma_f32_16x16x32_bf16(av[i], bv[j], acc[i][j], 0, 0, 0);
    }
    __syncthreads();
  }
#pragma unroll
  for (int i = 0; i < 4; i++)
#pragma unroll
    for (int j = 0; j < 4; j++) {
      int p = pb + wn + j * 16 + lane16;
      int c0 = mb + wm + i * 16 + lg * 4;
      union { short s[4]; short4 v; } u;
#pragma unroll
      for (int r = 0; r < 4; r++) {
        float g = feat[((size_t)(n * CH) + c0 + r) * HW + p] + acc[i][j][r] + b3[c0 + r];
        u.s[r] = f2bf(g > 0.f ? g : 0.f);
      }
      *(short4*)(goutT + ((size_t)(n * HW) + p) * CH + c0) = u.v;
    }
}

// ---------------- final MFMA: out = fs*(wf@[slf;gout]) + fb (K_STEP=64) ----------------
// A (wfb, 1MB L2-resident, linear) loaded DIRECTLY into fragments — no LDS for A.
// B (slfbT/goutT rows) via DMA into lB (coalesced). LDS ops/thread/step: 24 -> 12.
__launch_bounds__(256)
__global__ void final_mfma(const short* __restrict__ wfb, const short* __restrict__ slfbT,
                           const int h0, const short* __restrict__ goutT,
                           const float* __restrict__ fs, const float* __restrict__ fb,
                           float* __restrict__ out) {
  const int h = blockIdx.x + h0;       // h0..h0+63
  const int pb = h * WWi;
  const int mb = blockIdx.y * 128;
  const int n = blockIdx.z;
  const int t = threadIdx.x;
  const int lane16 = t & 15, lg = (t >> 4) & 3, wave = t >> 6;
  const int wm = (wave >> 1) * 64, wn = (wave & 1) * 64;
  __shared__ __align__(16) short lB[8192];
  const short* slfRows = slfbT + ((size_t)(n * 64) + (h - h0)) * WWi * CH;  // [w][c] rows
  const short* goutRows = goutT + ((size_t)(n * HW) + pb) * CH;             // [p][c] rows
  const short* wfRows = wfb + (size_t)mb * 1024;
  f4 acc[4][4];
#pragma unroll
  for (int i = 0; i < 4; i++)
#pragma unroll
    for (int j = 0; j < 4; j++) acc[i][j] = (f4)0.f;

  for (int s = 0; s < 16; s++) {
    if (s < 8) stg64_dma(slfRows, CH, s * 64, lB, t);
    else       stg64_dma(goutRows, CH, (s - 8) * 64, lB, t);
    __syncthreads();
#pragma unroll
    for (int kk = 0; kk < 2; kk++) {
      bf8 avf[4], bvf[4];
#pragma unroll
      for (int i = 0; i < 4; i++) avf[i] = fragld_g(wfRows, 1024, s * 64, wm + i * 16 + lane16, kk, lg);
#pragma unroll
      for (int j = 0; j < 4; j++) bvf[j] = fragld64(lB, wn + j * 16 + lane16, kk, lg);
#pragma unroll
      for (int i = 0; i < 4; i++)
#pragma unroll
        for (int j = 0; j < 4; j++)
          acc[i][j] = __builtin_amdgcn_mfma_f32_16x16x32_bf16(avf[i], bvf[j], acc[i][j], 0, 0, 0);
    }
    __syncthreads();
  }
#pragma unroll
  for (int i = 0; i < 4; i++)
#pragma unroll
    for (int j = 0; j < 4; j++) {
      int p = pb + wn + j * 16 + lane16;
#pragma unroll
      for (int r = 0; r < 4; r++) {
        int m = mb + wm + i * 16 + lg * 4 + r;
        out[((size_t)(n * CH) + m) * HW + p] = fs[m] * acc[i][j][r] + fb[m];
      }
    }
}

extern "C" void kernel_launch(void* const* d_in, const int* in_sizes, int n_in,
                              void* d_out, int out_size, void* d_ws, size_t ws_size,
                              hipStream_t stream) {
  (void)in_sizes; (void)n_in; (void)out_size; (void)ws_size;
  const float* feat      = (const float*)d_in[0];
  const float* w_phi     = (const float*)d_in[1];
  const float* bn_phi_s  = (const float*)d_in[2];
  const float* bn_phi_b  = (const float*)d_in[3];
  const float* w_theta   = (const float*)d_in[4];
  const float* bn_theta_s= (const float*)d_in[5];
  const float* bn_theta_b= (const float*)d_in[6];
  const float* w_adj     = (const float*)d_in[7];
  const float* bn_adj_s  = (const float*)d_in[8];
  const float* bn_adj_b  = (const float*)d_in[9];
  const float* w_wg      = (const float*)d_in[10];
  const float* bn_wg_s   = (const float*)d_in[11];
  const float* bn_wg_b   = (const float*)d_in[12];
  const float* w_conv3   = (const float*)d_in[13];
  const float* bn3_s     = (const float*)d_in[14];
  const float* bn3_b     = (const float*)d_in[15];
  const float* w_l1      = (const float*)d_in[16];
  const float* bnl1_s    = (const float*)d_in[17];
  const float* bnl1_b    = (const float*)d_in[18];
  const float* w_l2      = (const float*)d_in[19];
  const float* bnl2_s    = (const float*)d_in[20];
  const float* bnl2_b    = (const float*)d_in[21];
  const float* w_l3      = (const float*)d_in[22];
  const float* bnl3_s    = (const float*)d_in[23];
  const float* bnl3_b    = (const float*)d_in[24];
  const float* gamma     = (const float*)d_in[25];
  const float* w_final   = (const float*)d_in[26];
  const float* bnf_s     = (const float*)d_in[27];
  const float* bnf_b     = (const float*)d_in[28];

  float* out = (float*)d_out;
  // d_out staging (dead before final_mfma writes out): l1, l2, l3, wthb
  float* l1 = out;                                   // 8388608 f
  float* l2 = l1 + (size_t)8388608;                  // 2097152 f
  float* l3 = l2 + (size_t)2097152;                  // 524288 f
  short* wthb = (short*)(l3 + (size_t)524288);       // 65536 bf16 (128KB)

  // ws layout — proven 125.5MB footprint
  float* ws   = (float*)d_ws;
  float* lcam = ws;                                   // 524288 f
  float* lrw  = lcam + (size_t)4 * 512 * 256;         // 4194304 f
  float* bm_region = lrw + (size_t)4 * 512 * 16 * 128;// 8388608 f (32MB)
  short* bmb  = (short*)bm_region;                    // 16.7MB used as bf16
  float* rsum = bm_region + (size_t)4 * 128 * 16384;  // 512 f
  float* M1   = rsum + 512;                           // 262144 f
  float* M1p_old = M1 + (size_t)4 * 512 * 128;        // 8MB region
  float* zidt = M1p_old + (size_t)8 * 4 * 512 * 128;  // (kept for layout)
  float* z3b  = zidt + (size_t)4 * 256 * 128;         // 131072 f
  float* z4b  = z3b + (size_t)4 * 256 * 128;          // 131072 f
  float* wzb  = z4b + (size_t)4 * 256 * 128;          // 262144 f
  short* gout = (short*)(wzb + (size_t)4 * 512 * 128);// 33554432 bf16 (64MB) — gout_T layout
  short* wfb  = (short*)M1p_old;                      // 1MB, dead-region alias (late)
  float* m1p  = (float*)gout;                         // 33.5MB split-K partials (early, kc=32)
  float* energy = (float*)M1p_old;                    // 4MB, dead by wfb time
  short* slfb = (short*)bm_region;                    // 32MB slf half-tile (bmb dead by then) — slfb_T layout

  // local branch (4 outputs/thread depthwise conv)
  dw_conv_bn4<<<dim3(4 * 512 * 64 * 16 / 256), 256, 0, stream>>>(feat, l1, w_l1, bnl1_s, bnl1_b, 128, 128, 64, 16);
  dw_conv_bn4<<<dim3(4 * 512 * 32 * 8 / 256), 256, 0, stream>>>(l1, l2, w_l2, bnl2_s, bnl2_b, 64, 64, 32, 8);
  dw_conv_bn4<<<dim3(4 * 512 * 16 * 4 / 256), 256, 0, stream>>>(l2, l3, w_l3, bnl3_s, bnl3_b, 32, 32, 16, 4);
  // CAM via MFMA
  energy_mfma<<<dim3(4, 4, 4), 256, 0, stream>>>(l3, energy);
  softmax_attn<<<dim3(4 * 512), 256, 0, stream>>>(energy);
  cam_mfma<<<dim3(2, 4, 4), 256, 0, stream>>>(energy, l3, gamma, lcam);
  lrow_kernel<<<dim3(4 * 512 * 16 * 128 / 256), 256, 0, stream>>>(lcam, lrw);

  // graph branch (MFMA, K_STEP=64)
  cvt_f32_bf16<<<dim3(64), 256, 0, stream>>>(w_theta, wthb, 16384);
  theta_mfma2<<<dim3(128, 4), 256, 0, stream>>>(wthb, feat, bn_theta_s, bn_theta_b, bmb);
  rowsum_bf<<<dim3(512), 256, 0, stream>>>(bmb, rsum);
  m1_mfma2<<<dim3(4, 32, 4), 256, 0, stream>>>(feat, bmb, m1p);
  m1_reduce<<<dim3(1024), 256, 0, stream>>>(m1p, M1);
  z3_fused<<<dim3(256, 4), 128, 0, stream>>>(M1, w_phi, bn_phi_s, bn_phi_b, rsum, w_adj, bn_adj_s, bn_adj_b, z3b);
  z4_kernel<<<dim3(256, 4), 128, 0, stream>>>(z3b, w_wg, bn_wg_s, bn_wg_b, z4b);
  wz_kernel<<<dim3(512, 4), 128, 0, stream>>>(z4b, w_conv3, bn3_s, wzb);
  ygout_mfma2<<<dim3(128, 4, 4), 256, 0, stream>>>(wzb, bmb, feat, bn3_b, gout);  // writes gout_T; last bmb use

  // wfb convert (energy region now dead)
  cvt_f32_bf16<<<dim3(512), 256, 0, stream>>>(w_final, wfb, 131072);

  // final MFMA in two h-halves; slfb_T (32MB) reuses the dead bm region
  slf_build_T<<<dim3(8, 64, 4), 256, 0, stream>>>(feat, lrw, slfb, 0);
  final_mfma<<<dim3(64, 4, 4), 256, 0, stream>>>(wfb, slfb, 0, gout, bnf_s, bnf_b, out);
  slf_build_T<<<dim3(8, 64, 4), 256, 0, stream>>>(feat, lrw, slfb, 64);
  final_mfma<<<dim3(64, 4, 4), 256, 0, stream>>>(wfb, slfb, 64, gout, bnf_s, bnf_b, out);
}

// Round 12
// 453.087 us; speedup vs baseline: 1.1665x; 1.1665x over previous
//
#include <hip/hip_runtime.h>
#include <hip/hip_bf16.h>
#include <cstddef>
#include <cstdint>

// Problem constants
static constexpr int NB  = 4;       // batch
static constexpr int CH  = 512;     // planes
static constexpr int HH  = 128;
static constexpr int WWi = 128;
static constexpr int HW  = HH * WWi;   // 16384
static constexpr int Qd  = 128;     // q
static constexpr int Q2d = 256;     // 2q

typedef __attribute__((ext_vector_type(8))) short bf8;   // 8 bf16 (4 VGPRs)
typedef __attribute__((ext_vector_type(4))) float f4;    // MFMA accumulator

__device__ __forceinline__ short f2bf(float x) {
  __hip_bfloat16 h = __float2bfloat16(x);
  short s; __builtin_memcpy(&s, &h, 2); return s;
}
__device__ __forceinline__ float bfs2f(short u) {
  union { unsigned int i; float f; } x;
  x.i = ((unsigned int)(unsigned short)u) << 16; return x.f;
}

// ---------------- depthwise 3x3 stride-2 conv + BN, 4 outputs/thread (validated R5) ----------------
__launch_bounds__(256)
__global__ void dw_conv_bn4(const float* __restrict__ in, float* __restrict__ out,
                            const float* __restrict__ wgt, const float* __restrict__ s,
                            const float* __restrict__ b, int Hi, int Wi, int Ho, int Wo4) {
  int idx = blockIdx.x * 256 + threadIdx.x;   // NB*CH*Ho*Wo4
  int q = idx % Wo4; int t = idx / Wo4;
  int ho = t % Ho; t /= Ho;
  int c = t % CH;
  const float* ip = in + (size_t)t * Hi * Wi;
  const float* wp = wgt + c * 9;
  float w[9];
#pragma unroll
  for (int k = 0; k < 9; k++) w[k] = wp[k];
  const int x0 = q * 8;
  float acc0 = 0.f, acc1 = 0.f, acc2 = 0.f, acc3 = 0.f;
#pragma unroll
  for (int kh = 0; kh < 3; kh++) {
    int y = ho * 2 - 1 + kh;
    if ((unsigned)y < (unsigned)Hi) {
      const float* row = ip + (size_t)y * Wi + x0;
      float4 v0 = *(const float4*)row;
      float4 v1 = *(const float4*)(row + 4);
      float left = (x0 > 0) ? row[-1] : 0.f;
      float xs[9] = {left, v0.x, v0.y, v0.z, v0.w, v1.x, v1.y, v1.z, v1.w};
      const float w0 = w[kh * 3 + 0], w1 = w[kh * 3 + 1], w2 = w[kh * 3 + 2];
      acc0 += w0 * xs[0] + w1 * xs[1] + w2 * xs[2];
      acc1 += w0 * xs[2] + w1 * xs[3] + w2 * xs[4];
      acc2 += w0 * xs[4] + w1 * xs[5] + w2 * xs[6];
      acc3 += w0 * xs[6] + w1 * xs[7] + w2 * xs[8];
    }
  }
  const float sc = s[c], bb = b[c];
  float4 o;
  o.x = acc0 * sc + bb; o.y = acc1 * sc + bb;
  o.z = acc2 * sc + bb; o.w = acc3 * sc + bb;
  *(float4*)(out + (size_t)idx * 4) = o;
}

// ---------------- horizontal bilinear expand (validated) ----------------
__launch_bounds__(256)
__global__ void lrow_kernel(const float* __restrict__ lcam, float* __restrict__ lrow) {
  int idx = blockIdx.x * 256 + threadIdx.x;  // 4*512*16*128
  int wcol = idx & 127; int t = idx >> 7;
  int hy = t & 15; t >>= 4;
  float pos = wcol * (15.f / 127.f);
  int x0 = (int)pos; if (x0 > 15) x0 = 15;
  float tx = pos - x0;
  int x1 = x0 + 1; if (x1 > 15) x1 = 15;
  const float* lc = lcam + ((size_t)t * 16 + hy) * 16;
  lrow[idx] = lc[x0] * (1.f - tx) + lc[x1] * tx;
}

// ---------------- f32 -> bf16 convert (validated) ----------------
__launch_bounds__(256)
__global__ void cvt_f32_bf16(const float* __restrict__ in, short* __restrict__ out, int n4) {
  int i = blockIdx.x * 256 + threadIdx.x;
  if (i >= n4) return;
  float4 v = ((const float4*)in)[i];
  short tmp[4] = {f2bf(v.x), f2bf(v.y), f2bf(v.z), f2bf(v.w)};
  short4 o; __builtin_memcpy(&o, tmp, 8);
  ((short4*)out)[i] = o;
}

// ---------------- MFMA staging helpers, K_STEP = 64 (round-0, conflict-free) ----------------
// LDS tile [128 rows][64 k] bf16 (16KB); 8 16B-slots/row.
// Round-9 swizzle: perm = slot ^ (((row>>1) ^ (row>>3)) & 7).
// Reads stay 2-way (free). DO NOT pack transpose writes wider (R1 regression).
// DO NOT force occupancy via launch_bounds min-waves (R3 regression: scratch spills).
// DO NOT add secondary transposed outputs to MFMA epilogues (R8 regression).
// R10: counted-vmcnt pipelining = neutral (latency already hidden by 3 blocks/CU).
// R11: direct-global fragment loads = REGRESSION (VMEM latency lands on the
// compute critical path; the LDS round-trip is latency compression, not waste).
__device__ __forceinline__ int sls(int row, int slot) {
  return row * 64 + ((slot ^ (((row >> 1) ^ (row >> 3)) & 7)) << 3);
}

// DMA stage via global_load_lds (16B): linear LDS dest + INVERSE-swizzled
// per-lane global source (T21: both-sides-or-neither; XOR is an involution).
// LDS byte image == sls layout, so the fragld64 read path is unchanged.
__device__ __forceinline__ void stg64_dma(const short* __restrict__ src, size_t stride,
                                          int kb, short* lds, int t) {
  const int lane = t & 63, w = t >> 6;
#pragma unroll
  for (int i2 = 0; i2 < 4; i2++) {
    int r0 = w * 32 + i2 * 8;                 // wave-uniform base row
    int row = r0 + (lane >> 3);
    int sl = (lane & 7) ^ (((row >> 1) ^ (row >> 3)) & 7);
    const short* g = src + (size_t)row * stride + kb + sl * 8;
    short* l = lds + r0 * 64;                 // wave-uniform; HW adds lane*16B
    __builtin_amdgcn_global_load_lds(
        (const __attribute__((address_space(1))) unsigned int*)g,
        (__attribute__((address_space(3))) unsigned int*)l, 16, 0, 0);
  }
}

// contiguous bf16 source rows (VGPR path; kept for non-DMA users)
__device__ __forceinline__ void stg64_b16(const short* __restrict__ src, size_t stride,
                                          int kb, short* lds, int t) {
#pragma unroll
  for (int i = 0; i < 4; i++) {
    int chunk = t + i * 256;            // 1024 chunks = 128 rows x 8 slots
    int row = chunk >> 3, slot = chunk & 7;
    bf8 v = *(const bf8*)(src + (size_t)row * stride + kb + slot * 8);
    *(bf8*)(lds + sls(row, slot)) = v;
  }
}
// contiguous f32 source rows + cvt
__device__ __forceinline__ void stg64_f32(const float* __restrict__ src, size_t stride,
                                          int kb, short* lds, int t) {
#pragma unroll
  for (int i = 0; i < 4; i++) {
    int chunk = t + i * 256;
    int row = chunk >> 3, slot = chunk & 7;
    const float* sp = src + (size_t)row * stride + kb + slot * 8;
    float4 v0 = *(const float4*)sp, v1 = *(const float4*)(sp + 4);
    union { short s[8]; bf8 v; } u;
    u.s[0] = f2bf(v0.x); u.s[1] = f2bf(v0.y); u.s[2] = f2bf(v0.z); u.s[3] = f2bf(v0.w);
    u.s[4] = f2bf(v1.x); u.s[5] = f2bf(v1.y); u.s[6] = f2bf(v1.z); u.s[7] = f2bf(v1.w);
    *(bf8*)(lds + sls(row, slot)) = u.v;
  }
}
// f32 TRANSPOSE stage (coalesced): lds[p][c] <- src[c][pb+p]
__device__ __forceinline__ void stg64_t32(const float* __restrict__ src, size_t sstride,
                                          int pb, short* lds, int t) {
#pragma unroll
  for (int i2 = 0; i2 < 4; i2++) {
    int chunk = t + i2 * 256;           // 1024 chunks = 64 c x 16 p-groups
    int c = (chunk >> 3) & 63;
    int p8 = ((chunk & 7) | ((chunk >> 6) & 8)) * 8;
    const float* fr = src + (size_t)c * sstride + pb + p8;
    float4 f0 = *(const float4*)fr, f1 = *(const float4*)(fr + 4);
    float fv[8];
    __builtin_memcpy(&fv[0], &f0, 16); __builtin_memcpy(&fv[4], &f1, 16);
    int slot = c >> 3, eidx = c & 7;
#pragma unroll
    for (int e = 0; e < 8; e++) {
      lds[sls(p8 + e, slot) + eidx] = f2bf(fv[e]);
    }
  }
}
// bf16 TRANSPOSE stage (coalesced): lds[p][c] <- src[c][pb+p]
__device__ __forceinline__ void stg64_t16(const short* __restrict__ src, size_t sstride,
                                          int pb, short* lds, int t) {
#pragma unroll
  for (int i2 = 0; i2 < 4; i2++) {
    int chunk = t + i2 * 256;
    int c = (chunk >> 3) & 63;
    int p8 = ((chunk & 7) | ((chunk >> 6) & 8)) * 8;
    bf8 v = *(const bf8*)(src + (size_t)c * sstride + pb + p8);
    int slot = c >> 3, eidx = c & 7;
#pragma unroll
    for (int e = 0; e < 8; e++) {
      lds[sls(p8 + e, slot) + eidx] = v[e];
    }
  }
}
__device__ __forceinline__ bf8 fragld64(const short* lds, int row, int kk, int lg) {
  return *(const bf8*)(lds + sls(row, kk * 4 + lg));
}

// ---------------- slf precompute (TRANSPOSED): slfb_T[n][h'][w][c] (validated R6) ----------------
__launch_bounds__(256)
__global__ void slf_build_T(const float* __restrict__ feat, const float* __restrict__ lrw,
                            short* __restrict__ slfbT, int h0) {
  const int cb = blockIdx.x * 64;     // c block (8 of 512)
  const int hh = blockIdx.y;          // h' 0..63
  const int n  = blockIdx.z;
  const int h  = hh + h0;
  const int t  = threadIdx.x;
  __shared__ __align__(16) short lT[8192];   // [w=128][c=64] swizzled
  const float posy = h * (15.f / 127.f);
  int hy0 = (int)posy; if (hy0 > 15) hy0 = 15;
  int hy1 = hy0 + 1; if (hy1 > 15) hy1 = 15;
  const float tyv = posy - hy0;
#pragma unroll
  for (int i2 = 0; i2 < 4; i2++) {
    int chunk = t + i2 * 256;           // 64 c x 16 w-groups
    int c = (chunk >> 3) & 63;
    int w8 = ((chunk & 7) | ((chunk >> 6) & 8)) * 8;
    size_t cidx = (size_t)(n * CH) + cb + c;
    const float* fr = feat + cidx * HW + h * WWi + w8;
    const float* l0r = lrw + (cidx * 16 + hy0) * WWi + w8;
    const float* l1r = lrw + (cidx * 16 + hy1) * WWi + w8;
    float4 f0 = *(const float4*)fr, f1 = *(const float4*)(fr + 4);
    float4 a0 = *(const float4*)l0r, a1 = *(const float4*)(l0r + 4);
    float4 b0 = *(const float4*)l1r, b1 = *(const float4*)(l1r + 4);
    float fv[8], av[8], bv[8];
    __builtin_memcpy(&fv[0], &f0, 16); __builtin_memcpy(&fv[4], &f1, 16);
    __builtin_memcpy(&av[0], &a0, 16); __builtin_memcpy(&av[4], &a1, 16);
    __builtin_memcpy(&bv[0], &b0, 16); __builtin_memcpy(&bv[4], &b1, 16);
    int slot = c >> 3, eidx = c & 7;
#pragma unroll
    for (int e = 0; e < 8; e++) {
      float v = fv[e] * (1.f + av[e] + (bv[e] - av[e]) * tyv);
      lT[sls(w8 + e, slot) + eidx] = f2bf(v);
    }
  }
  __syncthreads();
#pragma unroll
  for (int i2 = 0; i2 < 4; i2++) {
    int chunk = t + i2 * 256;           // 128 w x 8 slots
    int w = chunk >> 3, slot = chunk & 7;
    bf8 v = *(const bf8*)(lT + sls(w, slot));
    *(bf8*)(slfbT + (((size_t)(n * 64) + hh) * WWi + w) * CH + cb + slot * 8) = v;
  }
}

// ---------------- CAM via MFMA (validated r8) ----------------
__launch_bounds__(256)
__global__ void energy_mfma(const float* __restrict__ l3, float* __restrict__ energy) {
  const int c0 = blockIdx.x * 128;
  const int d0 = blockIdx.y * 128;
  const int n = blockIdx.z;
  const int t = threadIdx.x;
  const int lane16 = t & 15, lg = (t >> 4) & 3, wave = t >> 6;
  const int wm = (wave >> 1) * 64, wn = (wave & 1) * 64;
  __shared__ __align__(16) short lA[8192], lB[8192];
  const float* srcA = l3 + ((size_t)n * CH + c0) * 256;
  const float* srcB = l3 + ((size_t)n * CH + d0) * 256;
  f4 acc[4][4];
#pragma unroll
  for (int i = 0; i < 4; i++)
#pragma unroll
    for (int j = 0; j < 4; j++) acc[i][j] = (f4)0.f;
  for (int kb = 0; kb < 256; kb += 64) {
    stg64_f32(srcA, 256, kb, lA, t);
    stg64_f32(srcB, 256, kb, lB, t);
    __syncthreads();
#pragma unroll
    for (int kk = 0; kk < 2; kk++) {
      bf8 av[4], bv[4];
#pragma unroll
      for (int i = 0; i < 4; i++) av[i] = fragld64(lA, wm + i * 16 + lane16, kk, lg);
#pragma unroll
      for (int j = 0; j < 4; j++) bv[j] = fragld64(lB, wn + j * 16 + lane16, kk, lg);
#pragma unroll
      for (int i = 0; i < 4; i++)
#pragma unroll
        for (int j = 0; j < 4; j++)
          acc[i][j] = __builtin_amdgcn_mfma_f32_16x16x32_bf16(av[i], bv[j], acc[i][j], 0, 0, 0);
    }
    __syncthreads();
  }
#pragma unroll
  for (int i = 0; i < 4; i++)
#pragma unroll
    for (int j = 0; j < 4; j++) {
      int d = d0 + wn + j * 16 + lane16;
#pragma unroll
      for (int r = 0; r < 4; r++) {
        int c = c0 + wm + i * 16 + lg * 4 + r;
        energy[((size_t)n * CH + c) * CH + d] = acc[i][j][r];
      }
    }
}

__launch_bounds__(256)
__global__ void softmax_attn(float* __restrict__ energy) {
  float* row = energy + (size_t)blockIdx.x * CH;   // 2048 rows of 512
  int t = threadIdx.x;
  __shared__ float red[256];
  float e0 = row[t], e1 = row[t + 256];
  red[t] = fminf(e0, e1);
  __syncthreads();
  for (int s = 128; s > 0; s >>= 1) {
    if (t < s) red[t] = fminf(red[t], red[t + s]);
    __syncthreads();
  }
  float emin = red[0];
  __syncthreads();
  float w0 = __expf(emin - e0), w1 = __expf(emin - e1);
  red[t] = w0 + w1;
  __syncthreads();
  for (int s = 128; s > 0; s >>= 1) {
    if (t < s) red[t] += red[t + s];
    __syncthreads();
  }
  float inv = 1.f / red[0];
  row[t] = w0 * inv;
  row[t + 256] = w1 * inv;
}

__launch_bounds__(256)
__global__ void cam_mfma(const float* __restrict__ attn, const float* __restrict__ l3,
                         const float* __restrict__ gamma, float* __restrict__ lcam) {
  const int pb = blockIdx.x * 128;
  const int mb = blockIdx.y * 128;
  const int n = blockIdx.z;
  const int t = threadIdx.x;
  const int lane16 = t & 15, lg = (t >> 4) & 3, wave = t >> 6;
  const int wm = (wave >> 1) * 64, wn = (wave & 1) * 64;
  __shared__ __align__(16) short lA[8192], lB[8192];
  const float* srcA = attn + ((size_t)n * CH + mb) * CH;
  const float gm = gamma[0];
  f4 acc[4][4];
#pragma unroll
  for (int i = 0; i < 4; i++)
#pragma unroll
    for (int j = 0; j < 4; j++) acc[i][j] = (f4)0.f;
  for (int kb = 0; kb < 512; kb += 64) {
    stg64_f32(srcA, CH, kb, lA, t);                                     // A: attn[c][d]
    stg64_t32(l3 + ((size_t)n * CH + kb) * 256, 256, pb, lB, t);        // B: l3[d][p] -> [p][d]
    __syncthreads();
#pragma unroll
    for (int kk = 0; kk < 2; kk++) {
      bf8 av[4], bv[4];
#pragma unroll
      for (int i = 0; i < 4; i++) av[i] = fragld64(lA, wm + i * 16 + lane16, kk, lg);
#pragma unroll
      for (int j = 0; j < 4; j++) bv[j] = fragld64(lB, wn + j * 16 + lane16, kk, lg);
#pragma unroll
      for (int i = 0; i < 4; i++)
#pragma unroll
        for (int j = 0; j < 4; j++)
          acc[i][j] = __builtin_amdgcn_mfma_f32_16x16x32_bf16(av[i], bv[j], acc[i][j], 0, 0, 0);
    }
    __syncthreads();
  }
#pragma unroll
  for (int i = 0; i < 4; i++)
#pragma unroll
    for (int j = 0; j < 4; j++) {
      int p = pb + wn + j * 16 + lane16;
#pragma unroll
      for (int r = 0; r < 4; r++) {
        int c = mb + wm + i * 16 + lg * 4 + r;
        size_t idx = ((size_t)n * CH + c) * 256 + p;
        lcam[idx] = gm * acc[i][j][r] + l3[idx];
      }
    }
}

// ---------------- theta MFMA: bmb[n][d][p] bf16 = s*(wth@feat) + b ----------------
__launch_bounds__(256)
__global__ void theta_mfma2(const short* __restrict__ wthb, const float* __restrict__ feat,
                            const float* __restrict__ s, const float* __restrict__ b,
                            short* __restrict__ bmb) {
  const int pb = blockIdx.x * 128;
  const int n = blockIdx.y;
  const int t = threadIdx.x;
  const int lane16 = t & 15, lg = (t >> 4) & 3, wave = t >> 6;
  const int wm = (wave >> 1) * 64, wn = (wave & 1) * 64;
  __shared__ __align__(16) short lA[8192], lB[8192];
  f4 acc[4][4];
#pragma unroll
  for (int i = 0; i < 4; i++)
#pragma unroll
    for (int j = 0; j < 4; j++) acc[i][j] = (f4)0.f;
  for (int kb = 0; kb < 512; kb += 64) {
    stg64_dma(wthb, 512, kb, lA, t);                                  // A: wth[d][c] (DMA)
    stg64_t32(feat + ((size_t)(n * CH) + kb) * HW, HW, pb, lB, t);    // B: feat[c][p] -> [p][c]
    __syncthreads();
#pragma unroll
    for (int kk = 0; kk < 2; kk++) {
      bf8 av[4], bv[4];
#pragma unroll
      for (int i = 0; i < 4; i++) av[i] = fragld64(lA, wm + i * 16 + lane16, kk, lg);
#pragma unroll
      for (int j = 0; j < 4; j++) bv[j] = fragld64(lB, wn + j * 16 + lane16, kk, lg);
#pragma unroll
      for (int i = 0; i < 4; i++)
#pragma unroll
        for (int j = 0; j < 4; j++)
          acc[i][j] = __builtin_amdgcn_mfma_f32_16x16x32_bf16(av[i], bv[j], acc[i][j], 0, 0, 0);
    }
    __syncthreads();
  }
#pragma unroll
  for (int i = 0; i < 4; i++)
#pragma unroll
    for (int j = 0; j < 4; j++) {
      int p = pb + wn + j * 16 + lane16;
#pragma unroll
      for (int r = 0; r < 4; r++) {
        int d = wm + i * 16 + lg * 4 + r;
        bmb[((size_t)(n * Qd) + d) * HW + p] = f2bf(s[d] * acc[i][j][r] + b[d]);
      }
    }
}

// ---------------- rowsum over bf16 rows ----------------
__launch_bounds__(256)
__global__ void rowsum_bf(const short* __restrict__ bmb, float* __restrict__ rs) {
  int row = blockIdx.x;   // 512 rows (n*Qd + d)
  int t = threadIdx.x;
  const short* r = bmb + (size_t)row * HW;
  float a = 0.f;
  for (int p = t * 8; p < HW; p += 2048) {
    bf8 v = *(const bf8*)(r + p);
#pragma unroll
    for (int e = 0; e < 8; e++) a += bfs2f(v[e]);
  }
  __shared__ float red[256];
  red[t] = a;
  __syncthreads();
  for (int s = 128; s > 0; s >>= 1) {
    if (t < s) red[t] += red[t + s];
    __syncthreads();
  }
  if (t == 0) rs[row] = red[0];
}

// ---------------- M1 MFMA: m1p[kc][n][c][d] = feat @ bmb^T partials (kc=32) ----------------
__launch_bounds__(256)
__global__ void m1_mfma2(const float* __restrict__ feat, const short* __restrict__ bmb,
                         float* __restrict__ m1p) {
  const int c0 = blockIdx.x * 128;
  const int kc = blockIdx.y;
  const int n = blockIdx.z;
  const int t = threadIdx.x;
  const int lane16 = t & 15, lg = (t >> 4) & 3, wave = t >> 6;
  const int wm = (wave >> 1) * 64, wn = (wave & 1) * 64;
  __shared__ __align__(16) short lA[8192], lB[8192];
  const float* srcA = feat + ((size_t)(n * CH) + c0) * HW;
  const short* srcB = bmb + (size_t)(n * Qd) * HW;
  f4 acc[4][4];
#pragma unroll
  for (int i = 0; i < 4; i++)
#pragma unroll
    for (int j = 0; j < 4; j++) acc[i][j] = (f4)0.f;
  const int kend = kc * 512 + 512;
  for (int kb = kc * 512; kb < kend; kb += 64) {
    stg64_f32(srcA, HW, kb, lA, t);   // A: feat[c][pos]
    stg64_dma(srcB, HW, kb, lB, t);   // B: bmb[d][pos] (DMA)
    __syncthreads();
#pragma unroll
    for (int kk = 0; kk < 2; kk++) {
      bf8 av[4], bv[4];
#pragma unroll
      for (int i = 0; i < 4; i++) av[i] = fragld64(lA, wm + i * 16 + lane16, kk, lg);
#pragma unroll
      for (int j = 0; j < 4; j++) bv[j] = fragld64(lB, wn + j * 16 + lane16, kk, lg);
#pragma unroll
      for (int i = 0; i < 4; i++)
#pragma unroll
        for (int j = 0; j < 4; j++)
          acc[i][j] = __builtin_amdgcn_mfma_f32_16x16x32_bf16(av[i], bv[j], acc[i][j], 0, 0, 0);
    }
    __syncthreads();
  }
#pragma unroll
  for (int i = 0; i < 4; i++)
#pragma unroll
    for (int j = 0; j < 4; j++) {
      int d = wn + j * 16 + lane16;
#pragma unroll
      for (int r = 0; r < 4; r++) {
        int c = c0 + wm + i * 16 + lg * 4 + r;
        m1p[(((size_t)kc * NB + n) * CH + c) * Qd + d] = acc[i][j][r];
      }
    }
}

__launch_bounds__(256)
__global__ void m1_reduce(const float* __restrict__ m1p, float* __restrict__ m1) {
  int idx = blockIdx.x * 256 + threadIdx.x;  // 4*512*128
  float a = 0.f;
#pragma unroll
  for (int kc = 0; kc < 32; kc++) a += m1p[(size_t)kc * (NB * CH * Qd) + idx];
  m1[idx] = a;
}

// ---------------- fused zidt+z3 (validated R8/R9) ----------------
__launch_bounds__(128)
__global__ void z3_fused(const float* __restrict__ m1, const float* __restrict__ wphi,
                         const float* __restrict__ sp, const float* __restrict__ bp,
                         const float* __restrict__ rs, const float* __restrict__ wadj,
                         const float* __restrict__ sa, const float* __restrict__ ba,
                         float* __restrict__ z3) {
  int n = blockIdx.y, c = blockIdx.x, d = threadIdx.x;
  __shared__ float wrow[512];
  __shared__ float zr[128];
  for (int i = d; i < 512; i += 128) wrow[i] = wphi[(size_t)c * 512 + i];
  __syncthreads();
  const float* mb = m1 + (size_t)n * CH * Qd;
  float acc = 0.f;
#pragma unroll 4
  for (int i = 0; i < 512; i++) acc += wrow[i] * mb[i * Qd + d];
  zr[d] = sp[c] * acc + bp[c] * rs[n * Qd + d];
  __syncthreads();
  const float* wr = wadj + (size_t)d * 128;
  float acc2 = 0.f;
#pragma unroll 4
  for (int i = 0; i < 128; i++) acc2 += wr[i] * zr[i];
  z3[((size_t)n * Q2d + c) * Qd + d] = sa[d] * acc2 + ba[d] + zr[d];
}

__launch_bounds__(128)
__global__ void z4_kernel(const float* __restrict__ z3, const float* __restrict__ wwg,
                          const float* __restrict__ sw, const float* __restrict__ bw,
                          float* __restrict__ z4) {
  int n = blockIdx.y, o = blockIdx.x, d = threadIdx.x;
  __shared__ float wrow[256];
  wrow[d] = wwg[(size_t)o * 256 + d];
  wrow[d + 128] = wwg[(size_t)o * 256 + 128 + d];
  __syncthreads();
  const float* zb = z3 + (size_t)n * Q2d * Qd;
  float acc = 0.f;
#pragma unroll 4
  for (int i = 0; i < 256; i++) acc += wrow[i] * zb[i * Qd + d];
  z4[((size_t)n * Q2d + o) * Qd + d] = sw[o] * acc + bw[o];
}

__launch_bounds__(128)
__global__ void wz_kernel(const float* __restrict__ z4, const float* __restrict__ wc3,
                          const float* __restrict__ s3, float* __restrict__ wz) {
  int n = blockIdx.y, o = blockIdx.x, d = threadIdx.x;
  __shared__ float wrow[256];
  wrow[d] = wc3[(size_t)o * 256 + d];
  wrow[d + 128] = wc3[(size_t)o * 256 + 128 + d];
  __syncthreads();
  const float* zb = z4 + (size_t)n * Q2d * Qd;
  float acc = 0.f;
#pragma unroll 4
  for (int i = 0; i < 256; i++) acc += wrow[i] * zb[i * Qd + d];
  wz[((size_t)n * CH + o) * Qd + d] = s3[o] * acc;
}

// ---------------- ygout MFMA: gout_T[n][p][c] bf16 = relu(feat + wz@bmb + b3) ----------------
__launch_bounds__(256)
__global__ void ygout_mfma2(const float* __restrict__ wz, const short* __restrict__ bmb,
                            const float* __restrict__ feat, const float* __restrict__ b3,
                            short* __restrict__ goutT) {
  const int pb = blockIdx.x * 128;
  const int mb = blockIdx.y * 128;
  const int n = blockIdx.z;
  const int t = threadIdx.x;
  const int lane16 = t & 15, lg = (t >> 4) & 3, wave = t >> 6;
  const int wm = (wave >> 1) * 64, wn = (wave & 1) * 64;
  __shared__ __align__(16) short lA[8192], lB[8192];
  const float* srcA = wz + ((size_t)(n * CH) + mb) * Qd;
  f4 acc[4][4];
#pragma unroll
  for (int i = 0; i < 4; i++)
#pragma unroll
    for (int j = 0; j < 4; j++) acc[i][j] = (f4)0.f;
  for (int kb = 0; kb < 128; kb += 64) {
    stg64_f32(srcA, Qd, kb, lA, t);                                   // A: wz[c][d]
    stg64_t16(bmb + ((size_t)(n * Qd) + kb) * HW, HW, pb, lB, t);     // B: bmb[d][p] -> [p][d]
    __syncthreads();
#pragma unroll
    for (int kk = 0; kk < 2; kk++) {
      bf8 av[4], bv[4];
#pragma unroll
      for (int i = 0; i < 4; i++) av[i] = fragld64(lA, wm + i * 16 + lane16, kk, lg);
#pragma unroll
      for (int j = 0; j < 4; j++) bv[j] = fragld64(lB, wn + j * 16 + lane16, kk, lg);
#pragma unroll
      for (int i = 0; i < 4; i++)
#pragma unroll
        for (int j = 0; j < 4; j++)
          acc[i][j] = __builtin_amdgcn_mfma_f32_16x16x32_bf16(av[i], bv[j], acc[i][j], 0, 0, 0);
    }
    __syncthreads();
  }
#pragma unroll
  for (int i = 0; i < 4; i++)
#pragma unroll
    for (int j = 0; j < 4; j++) {
      int p = pb + wn + j * 16 + lane16;
      int c0 = mb + wm + i * 16 + lg * 4;
      union { short s[4]; short4 v; } u;
#pragma unroll
      for (int r = 0; r < 4; r++) {
        float g = feat[((size_t)(n * CH) + c0 + r) * HW + p] + acc[i][j][r] + b3[c0 + r];
        u.s[r] = f2bf(g > 0.f ? g : 0.f);
      }
      *(short4*)(goutT + ((size_t)(n * HW) + p) * CH + c0) = u.v;
    }
}

// ---------------- final MFMA: out = fs*(wf@[slf;gout]) + fb (K_STEP=64, full-DMA staging) ----------------
__launch_bounds__(256)
__global__ void final_mfma(const short* __restrict__ wfb, const short* __restrict__ slfbT,
                           const int h0, const short* __restrict__ goutT,
                           const float* __restrict__ fs, const float* __restrict__ fb,
                           float* __restrict__ out) {
  const int h = blockIdx.x + h0;       // h0..h0+63
  const int pb = h * WWi;
  const int mb = blockIdx.y * 128;
  const int n = blockIdx.z;
  const int t = threadIdx.x;
  const int lane16 = t & 15, lg = (t >> 4) & 3, wave = t >> 6;
  const int wm = (wave >> 1) * 64, wn = (wave & 1) * 64;
  __shared__ __align__(16) short lA[8192], lB[8192];
  const short* slfRows = slfbT + ((size_t)(n * 64) + (h - h0)) * WWi * CH;  // [w][c] rows
  const short* goutRows = goutT + ((size_t)(n * HW) + pb) * CH;             // [p][c] rows
  f4 acc[4][4];
#pragma unroll
  for (int i = 0; i < 4; i++)
#pragma unroll
    for (int j = 0; j < 4; j++) acc[i][j] = (f4)0.f;

  for (int kb = 0; kb < 1024; kb += 64) {
    stg64_dma(wfb + (size_t)mb * 1024, 1024, kb, lA, t);
    if (kb < 512) {
      stg64_dma(slfRows, CH, kb, lB, t);          // slf half: rows w, contiguous c
    } else {
      stg64_dma(goutRows, CH, kb - 512, lB, t);   // g half: rows p, contiguous c
    }
    __syncthreads();
#pragma unroll
    for (int kk = 0; kk < 2; kk++) {
      bf8 avf[4], bvf[4];
#pragma unroll
      for (int i = 0; i < 4; i++) avf[i] = fragld64(lA, wm + i * 16 + lane16, kk, lg);
#pragma unroll
      for (int j = 0; j < 4; j++) bvf[j] = fragld64(lB, wn + j * 16 + lane16, kk, lg);
#pragma unroll
      for (int i = 0; i < 4; i++)
#pragma unroll
        for (int j = 0; j < 4; j++)
          acc[i][j] = __builtin_amdgcn_mfma_f32_16x16x32_bf16(avf[i], bvf[j], acc[i][j], 0, 0, 0);
    }
    __syncthreads();
  }
#pragma unroll
  for (int i = 0; i < 4; i++)
#pragma unroll
    for (int j = 0; j < 4; j++) {
      int p = pb + wn + j * 16 + lane16;
#pragma unroll
      for (int r = 0; r < 4; r++) {
        int m = mb + wm + i * 16 + lg * 4 + r;
        out[((size_t)(n * CH) + m) * HW + p] = fs[m] * acc[i][j][r] + fb[m];
      }
    }
}

extern "C" void kernel_launch(void* const* d_in, const int* in_sizes, int n_in,
                              void* d_out, int out_size, void* d_ws, size_t ws_size,
                              hipStream_t stream) {
  (void)in_sizes; (void)n_in; (void)out_size; (void)ws_size;
  const float* feat      = (const float*)d_in[0];
  const float* w_phi     = (const float*)d_in[1];
  const float* bn_phi_s  = (const float*)d_in[2];
  const float* bn_phi_b  = (const float*)d_in[3];
  const float* w_theta   = (const float*)d_in[4];
  const float* bn_theta_s= (const float*)d_in[5];
  const float* bn_theta_b= (const float*)d_in[6];
  const float* w_adj     = (const float*)d_in[7];
  const float* bn_adj_s  = (const float*)d_in[8];
  const float* bn_adj_b  = (const float*)d_in[9];
  const float* w_wg      = (const float*)d_in[10];
  const float* bn_wg_s   = (const float*)d_in[11];
  const float* bn_wg_b   = (const float*)d_in[12];
  const float* w_conv3   = (const float*)d_in[13];
  const float* bn3_s     = (const float*)d_in[14];
  const float* bn3_b     = (const float*)d_in[15];
  const float* w_l1      = (const float*)d_in[16];
  const float* bnl1_s    = (const float*)d_in[17];
  const float* bnl1_b    = (const float*)d_in[18];
  const float* w_l2      = (const float*)d_in[19];
  const float* bnl2_s    = (const float*)d_in[20];
  const float* bnl2_b    = (const float*)d_in[21];
  const float* w_l3      = (const float*)d_in[22];
  const float* bnl3_s    = (const float*)d_in[23];
  const float* bnl3_b    = (const float*)d_in[24];
  const float* gamma     = (const float*)d_in[25];
  const float* w_final   = (const float*)d_in[26];
  const float* bnf_s     = (const float*)d_in[27];
  const float* bnf_b     = (const float*)d_in[28];

  float* out = (float*)d_out;
  // d_out staging (dead before final_mfma writes out): l1, l2, l3, wthb
  float* l1 = out;                                   // 8388608 f
  float* l2 = l1 + (size_t)8388608;                  // 2097152 f
  float* l3 = l2 + (size_t)2097152;                  // 524288 f
  short* wthb = (short*)(l3 + (size_t)524288);       // 65536 bf16 (128KB)

  // ws layout — proven 125.5MB footprint
  float* ws   = (float*)d_ws;
  float* lcam = ws;                                   // 524288 f
  float* lrw  = lcam + (size_t)4 * 512 * 256;         // 4194304 f
  float* bm_region = lrw + (size_t)4 * 512 * 16 * 128;// 8388608 f (32MB)
  short* bmb  = (short*)bm_region;                    // 16.7MB used as bf16
  float* rsum = bm_region + (size_t)4 * 128 * 16384;  // 512 f
  float* M1   = rsum + 512;                           // 262144 f
  float* M1p_old = M1 + (size_t)4 * 512 * 128;        // 8MB region
  float* zidt = M1p_old + (size_t)8 * 4 * 512 * 128;  // (kept for layout)
  float* z3b  = zidt + (size_t)4 * 256 * 128;         // 131072 f
  float* z4b  = z3b + (size_t)4 * 256 * 128;          // 131072 f
  float* wzb  = z4b + (size_t)4 * 256 * 128;          // 262144 f
  short* gout = (short*)(wzb + (size_t)4 * 512 * 128);// 33554432 bf16 (64MB) — gout_T layout
  short* wfb  = (short*)M1p_old;                      // 1MB, dead-region alias (late)
  float* m1p  = (float*)gout;                         // 33.5MB split-K partials (early, kc=32)
  float* energy = (float*)M1p_old;                    // 4MB, dead by wfb time
  short* slfb = (short*)bm_region;                    // 32MB slf half-tile (bmb dead by then) — slfb_T layout

  // local branch (4 outputs/thread depthwise conv)
  dw_conv_bn4<<<dim3(4 * 512 * 64 * 16 / 256), 256, 0, stream>>>(feat, l1, w_l1, bnl1_s, bnl1_b, 128, 128, 64, 16);
  dw_conv_bn4<<<dim3(4 * 512 * 32 * 8 / 256), 256, 0, stream>>>(l1, l2, w_l2, bnl2_s, bnl2_b, 64, 64, 32, 8);
  dw_conv_bn4<<<dim3(4 * 512 * 16 * 4 / 256), 256, 0, stream>>>(l2, l3, w_l3, bnl3_s, bnl3_b, 32, 32, 16, 4);
  // CAM via MFMA
  energy_mfma<<<dim3(4, 4, 4), 256, 0, stream>>>(l3, energy);
  softmax_attn<<<dim3(4 * 512), 256, 0, stream>>>(energy);
  cam_mfma<<<dim3(2, 4, 4), 256, 0, stream>>>(energy, l3, gamma, lcam);
  lrow_kernel<<<dim3(4 * 512 * 16 * 128 / 256), 256, 0, stream>>>(lcam, lrw);

  // graph branch (MFMA, K_STEP=64)
  cvt_f32_bf16<<<dim3(64), 256, 0, stream>>>(w_theta, wthb, 16384);
  theta_mfma2<<<dim3(128, 4), 256, 0, stream>>>(wthb, feat, bn_theta_s, bn_theta_b, bmb);
  rowsum_bf<<<dim3(512), 256, 0, stream>>>(bmb, rsum);
  m1_mfma2<<<dim3(4, 32, 4), 256, 0, stream>>>(feat, bmb, m1p);
  m1_reduce<<<dim3(1024), 256, 0, stream>>>(m1p, M1);
  z3_fused<<<dim3(256, 4), 128, 0, stream>>>(M1, w_phi, bn_phi_s, bn_phi_b, rsum, w_adj, bn_adj_s, bn_adj_b, z3b);
  z4_kernel<<<dim3(256, 4), 128, 0, stream>>>(z3b, w_wg, bn_wg_s, bn_wg_b, z4b);
  wz_kernel<<<dim3(512, 4), 128, 0, stream>>>(z4b, w_conv3, bn3_s, wzb);
  ygout_mfma2<<<dim3(128, 4, 4), 256, 0, stream>>>(wzb, bmb, feat, bn3_b, gout);  // writes gout_T; last bmb use

  // wfb convert (energy region now dead)
  cvt_f32_bf16<<<dim3(512), 256, 0, stream>>>(w_final, wfb, 131072);

  // final MFMA in two h-halves; slfb_T (32MB) reuses the dead bm region
  slf_build_T<<<dim3(8, 64, 4), 256, 0, stream>>>(feat, lrw, slfb, 0);
  final_mfma<<<dim3(64, 4, 4), 256, 0, stream>>>(wfb, slfb, 0, gout, bnf_s, bnf_b, out);
  slf_build_T<<<dim3(8, 64, 4), 256, 0, stream>>>(feat, lrw, slfb, 64);
  final_mfma<<<dim3(64, 4, 4), 256, 0, stream>>>(wfb, slfb, 64, gout, bnf_s, bnf_b, out);
}